// Round 3
// baseline (132.286 us; speedup 1.0000x reference)
//
#include <hip/hip_runtime.h>
#include <hip/hip_bf16.h>

#define BS 16
#define NQ 200
#define NPTS 25
#define VOC 96
#define VOCP1 97
#define NGT 32
#define LSEQ 25
#define NCOL (BS*NGT)      // 512
#define NBQ (BS*NQ)        // 3200
#define KL_EPS 1e-6f
#define FOCAL_EPS 1e-8f

// ============ Launch A: blocks [0,3200) = per-(b,q) logP + focal cost
//              blocks [3200,3296) = soft_all[96,96] rows ============
__global__ __launch_bounds__(128) void kA(
        const float* __restrict__ pred_logits,       // [NBQ, 25]
        const float* __restrict__ pred_text_logits,  // [NBQ, 25, 97]
        const float* __restrict__ centroids,         // [96, 256]
        float* __restrict__ logP,                    // [NBQ, 96]
        float* __restrict__ cost_class,              // [NBQ]
        float* __restrict__ soft)                    // [96, 96]
{
    const int tid  = threadIdx.x;
    const int wave = tid >> 6, lane = tid & 63;
    __shared__ float s_buf[NPTS * VOCP1];   // k1: exp-logits; k2a: centroid row
    __shared__ float s_invden[NPTS];
    __shared__ float s_part[2];

    if (blockIdx.x < NBQ) {
        // ---------------- K1 body ----------------
        const int bq = blockIdx.x;
        const float* tl = pred_text_logits + (size_t)bq * NPTS * VOCP1;
        for (int i = tid; i < NPTS * VOCP1; i += 128)
            s_buf[i] = __expf(tl[i]);
        __syncthreads();

        // per-point softmax denominators: 4 subgroups of 32 lanes
        const int grp = tid >> 5, sub = tid & 31;
        for (int p0 = 0; p0 < NPTS; p0 += 4) {
            int p = p0 + grp;
            float s = 0.f;
            if (p < NPTS)
                for (int v = sub; v < VOCP1; v += 32) s += s_buf[p * VOCP1 + v];
            #pragma unroll
            for (int off = 16; off; off >>= 1) s += __shfl_xor(s, off, 32);
            if (p < NPTS && sub == 0) s_invden[p] = 1.0f / s;
        }

        // focal class cost on wave 0 (lanes 0..24 carry values)
        if (wave == 0) {
            float cc = 0.f;
            if (lane < NPTS) {
                float x = pred_logits[bq * NPTS + lane];
                float p = 1.f / (1.f + __expf(-x));
                float pos = 0.25f * (1.f - p) * (1.f - p) * (-__logf(p + FOCAL_EPS));
                float neg = 0.75f * p * p * (-__logf(1.f - p + FOCAL_EPS));
                cc = pos - neg;
            }
            #pragma unroll
            for (int off = 32; off; off >>= 1) cc += __shfl_xor(cc, off);
            if (lane == 0) cost_class[bq] = cc * (1.0f / NPTS);
        }
        __syncthreads();   // s_invden ready

        // averaged probability over points, v < 96
        float avg = 0.f;
        if (tid < VOC) {
            float a = 0.f;
            #pragma unroll
            for (int p = 0; p < NPTS; p++)
                a += s_buf[p * VOCP1 + tid] * s_invden[p];
            avg = a * (1.0f / NPTS);
        }
        float s = avg;
        #pragma unroll
        for (int off = 32; off; off >>= 1) s += __shfl_xor(s, off);
        if (lane == 0) s_part[wave] = s;
        __syncthreads();
        float denom = s_part[0] + s_part[1] + (float)VOC * KL_EPS;
        if (tid < VOC)
            logP[(size_t)bq * VOC + tid] = __logf((avg + KL_EPS) / denom);
    } else {
        // ---------------- K2a body: soft row i ----------------
        const int i = blockIdx.x - NBQ;
        for (int k = tid; k < 64; k += 128)
            *(float4*)&s_buf[k * 4] = *(const float4*)&centroids[i * 256 + k * 4];
        __syncthreads();

        float e = 0.f;
        if (tid < VOC) {
            float dij = 0.f, djj = 0.f, dii = 0.f;
            const float4* cj = (const float4*)(centroids + (size_t)tid * 256);
            #pragma unroll 4
            for (int k = 0; k < 64; k++) {
                float4 b = cj[k];
                float4 a = *(const float4*)&s_buf[k * 4];
                dij += a.x * b.x + a.y * b.y + a.z * b.z + a.w * b.w;
                djj += b.x * b.x + b.y * b.y + b.z * b.z + b.w * b.w;
                dii += a.x * a.x + a.y * a.y + a.z * a.z + a.w * a.w;
            }
            float sim = dij * rsqrtf(dii * djj);
            e = __expf(sim);
        }
        float s = e;
        #pragma unroll
        for (int off = 32; off; off >>= 1) s += __shfl_xor(s, off);
        if (lane == 0) s_part[wave] = s;
        __syncthreads();
        float den = s_part[0] + s_part[1];
        if (tid < VOC) {
            float v = 0.15f * e / den;
            if (tid == i) v += 0.85f;
            soft[i * VOC + tid] = v;
        }
    }
}

// ============ Launch C: final cost matrix, T computed in-block ============
// 256 blocks: 128 row-tiles (25 rows) x 2 col-chunks (256 cols).
__global__ __launch_bounds__(256) void kC(
        const float* __restrict__ pred_ctrl,   // [NBQ, 50]
        const float* __restrict__ tgt_ctrl,    // [512, 50]
        const float* __restrict__ logP,        // [NBQ, 96]
        const float* __restrict__ cost_class,  // [NBQ]
        const float* __restrict__ soft,        // [96, 96]
        const int* __restrict__ tgt_texts,     // [512, 25]
        float* __restrict__ out)               // [NBQ, 512]
{
    const int rt   = blockIdx.x >> 1;     // row tile 0..127
    const int ch   = blockIdx.x & 1;      // col chunk 0..1
    const int row0 = rt * NPTS;
    const int c0   = ch * 256;
    const int b    = rt >> 3;             // 8 row-tiles per batch
    const int tid  = threadIdx.x;

    __shared__ float s_pred[NPTS][52];
    __shared__ float s_logP[NPTS][VOC];
    __shared__ float s_T[NGT][VOCP1];
    __shared__ float s_text[NPTS][NGT + 1];
    __shared__ float s_cc[NPTS];
    __shared__ int   s_chars[NGT][LSEQ];
    __shared__ float s_TlogT[NGT];
    __shared__ int   s_len[NGT];

    const bool has_text = ((b < 8) == (ch == 0));   // b's 32 cols in this chunk
    const int  jb0 = b * NGT - c0;                  // local col where text starts

    // stage pred rows (coalesced flat copy) + cc
    const float* pg = pred_ctrl + (size_t)row0 * 50;
    for (int i = tid; i < NPTS * 50; i += 256) {
        int r = i / 50;
        s_pred[r][i - r * 50] = pg[i];
    }
    if (tid < NPTS) s_cc[tid] = cost_class[row0 + tid];
    if (has_text) {
        for (int i = tid; i < NPTS * VOC; i += 256) {
            int r = i / VOC, v = i - r * VOC;
            s_logP[r][v] = logP[(size_t)(row0 + r) * VOC + v];
        }
        for (int i = tid; i < NGT * LSEQ; i += 256) {
            int g = i / LSEQ, l = i - g * LSEQ;
            s_chars[g][l] = tgt_texts[(b * NGT + g) * LSEQ + l];
        }
    }

    // own column's tgt coords -> registers (float2: 200B stride, 8B aligned)
    float tg[50];
    {
        const float2* trow = (const float2*)(tgt_ctrl + (size_t)(c0 + tid) * 50);
        #pragma unroll
        for (int q = 0; q < 25; q++) {
            float2 v = trow[q];
            tg[2 * q] = v.x; tg[2 * q + 1] = v.y;
        }
    }
    __syncthreads();

    if (has_text) {
        // ---- inline K2b: T rows via 8 groups of 32 lanes, 3 v's per lane ----
        const int grp = tid >> 5, sub = tid & 31;
        for (int g = grp; g < NGT; g += 8) {
            int len = 0;
            float a0 = 0.f, a1 = 0.f, a2 = 0.f;
            for (int l = 0; l < LSEQ; l++) {
                int t = s_chars[g][l];
                if (t != VOC) {
                    len++;
                    const float* sr = soft + t * VOC;
                    a0 += sr[sub]; a1 += sr[sub + 32]; a2 += sr[sub + 64];
                }
            }
            float inv = 1.f / (float)(len > 0 ? len : 1);
            a0 *= inv; a1 *= inv; a2 *= inv;
            float s = a0 + a1 + a2;
            #pragma unroll
            for (int off = 16; off; off >>= 1) s += __shfl_xor(s, off, 32);
            float denom = s + (float)VOC * KL_EPS;
            float t0 = (a0 + KL_EPS) / denom;
            float t1 = (a1 + KL_EPS) / denom;
            float t2 = (a2 + KL_EPS) / denom;
            s_T[g][sub] = t0; s_T[g][sub + 32] = t1; s_T[g][sub + 64] = t2;
            float tl = t0 * __logf(t0) + t1 * __logf(t1) + t2 * __logf(t2);
            #pragma unroll
            for (int off = 16; off; off >>= 1) tl += __shfl_xor(tl, off, 32);
            if (sub == 0) { s_TlogT[g] = tl; s_len[g] = len; }
        }
        __syncthreads();

        // ---- text cost for the 25x32 matching pairs ----
        for (int i = tid; i < NPTS * NGT; i += 256) {
            int r = i >> 5, g = i & 31;
            float txt;
            if (s_len[g] == 0) {
                txt = 100.f;
            } else {
                float d0 = 0.f, d1 = 0.f;
                #pragma unroll
                for (int v = 0; v < VOC; v += 2) {
                    d0 += s_logP[r][v]     * s_T[g][v];
                    d1 += s_logP[r][v + 1] * s_T[g][v + 1];
                }
                txt = s_TlogT[g] - (d0 + d1);
            }
            s_text[r][g] = txt;
        }
        __syncthreads();
    }

    // ---- main loop: 25 rows, pred via LDS broadcast float4 ----
    for (int r = 0; r < NPTS; r++) {
        float kp0 = 0.f, kp1 = 0.f, kp2 = 0.f, kp3 = 0.f;
        #pragma unroll
        for (int q = 0; q < 12; q++) {
            float4 p = *(const float4*)&s_pred[r][q * 4];
            kp0 += fabsf(p.x - tg[q * 4 + 0]);
            kp1 += fabsf(p.y - tg[q * 4 + 1]);
            kp2 += fabsf(p.z - tg[q * 4 + 2]);
            kp3 += fabsf(p.w - tg[q * 4 + 3]);
        }
        kp0 += fabsf(s_pred[r][48] - tg[48]);
        kp1 += fabsf(s_pred[r][49] - tg[49]);
        float val = s_cc[r] + (kp0 + kp1) + (kp2 + kp3);
        if (has_text) {
            unsigned g = (unsigned)((int)tid - jb0);
            if (g < (unsigned)NGT) val += s_text[r][g];
        }
        out[(size_t)(row0 + r) * NCOL + (c0 + tid)] = val;
    }
}

extern "C" void kernel_launch(void* const* d_in, const int* in_sizes, int n_in,
                              void* d_out, int out_size, void* d_ws, size_t ws_size,
                              hipStream_t stream) {
    const float* pred_logits = (const float*)d_in[0];
    const float* pred_ctrl   = (const float*)d_in[1];
    const float* pred_text   = (const float*)d_in[2];
    const float* tgt_ctrl    = (const float*)d_in[3];
    const int*   tgt_texts   = (const int*)d_in[4];
    const float* centroids   = (const float*)d_in[5];
    float* out = (float*)d_out;

    float* ws        = (float*)d_ws;
    float* logP      = ws;                          // 3200*96
    float* costclass = logP + (size_t)NBQ * VOC;    // 3200
    float* soft      = costclass + NBQ;             // 96*96

    kA<<<NBQ + VOC, 128, 0, stream>>>(pred_logits, pred_text, centroids,
                                      logP, costclass, soft);
    kC<<<256, 256, 0, stream>>>(pred_ctrl, tgt_ctrl, logP, costclass,
                                soft, tgt_texts, out);
}

// Round 4
// 127.337 us; speedup vs baseline: 1.0389x; 1.0389x over previous
//
#include <hip/hip_runtime.h>
#include <hip/hip_bf16.h>

#define BS 16
#define NQ 200
#define NPTS 25
#define VOC 96
#define VOCP1 97
#define NGT 32
#define LSEQ 25
#define NCOL (BS*NGT)      // 512
#define NBQ (BS*NQ)        // 3200
#define KL_EPS 1e-6f
#define FOCAL_EPS 1e-8f

// ============ kA: blocks [0,3200) = per-(b,q) logP + focal cost
//              blocks [3200,3296) = soft_all[96,96] rows ============
__global__ __launch_bounds__(128) void kA(
        const float* __restrict__ pred_logits,       // [NBQ, 25]
        const float* __restrict__ pred_text_logits,  // [NBQ, 25, 97]
        const float* __restrict__ centroids,         // [96, 256]
        float* __restrict__ logP,                    // [NBQ, 96]
        float* __restrict__ cost_class,              // [NBQ]
        float* __restrict__ soft)                    // [96, 96]
{
    const int tid  = threadIdx.x;
    const int wave = tid >> 6, lane = tid & 63;
    __shared__ float s_buf[NPTS * VOCP1];
    __shared__ float s_invden[NPTS];
    __shared__ float s_part[2];

    if (blockIdx.x < NBQ) {
        const int bq = blockIdx.x;
        const float* tl = pred_text_logits + (size_t)bq * NPTS * VOCP1;
        for (int i = tid; i < NPTS * VOCP1; i += 128)
            s_buf[i] = __expf(tl[i]);
        __syncthreads();

        const int grp = tid >> 5, sub = tid & 31;
        for (int p0 = 0; p0 < NPTS; p0 += 4) {
            int p = p0 + grp;
            float s = 0.f;
            if (p < NPTS)
                for (int v = sub; v < VOCP1; v += 32) s += s_buf[p * VOCP1 + v];
            #pragma unroll
            for (int off = 16; off; off >>= 1) s += __shfl_xor(s, off, 32);
            if (p < NPTS && sub == 0) s_invden[p] = 1.0f / s;
        }

        if (wave == 0) {
            float cc = 0.f;
            if (lane < NPTS) {
                float x = pred_logits[bq * NPTS + lane];
                float p = 1.f / (1.f + __expf(-x));
                float pos = 0.25f * (1.f - p) * (1.f - p) * (-__logf(p + FOCAL_EPS));
                float neg = 0.75f * p * p * (-__logf(1.f - p + FOCAL_EPS));
                cc = pos - neg;
            }
            #pragma unroll
            for (int off = 32; off; off >>= 1) cc += __shfl_xor(cc, off);
            if (lane == 0) cost_class[bq] = cc * (1.0f / NPTS);
        }
        __syncthreads();

        float avg = 0.f;
        if (tid < VOC) {
            float a = 0.f;
            #pragma unroll
            for (int p = 0; p < NPTS; p++)
                a += s_buf[p * VOCP1 + tid] * s_invden[p];
            avg = a * (1.0f / NPTS);
        }
        float s = avg;
        #pragma unroll
        for (int off = 32; off; off >>= 1) s += __shfl_xor(s, off);
        if (lane == 0) s_part[wave] = s;
        __syncthreads();
        float denom = s_part[0] + s_part[1] + (float)VOC * KL_EPS;
        if (tid < VOC)
            logP[(size_t)bq * VOC + tid] = __logf((avg + KL_EPS) / denom);
    } else {
        const int i = blockIdx.x - NBQ;
        for (int k = tid; k < 64; k += 128)
            *(float4*)&s_buf[k * 4] = *(const float4*)&centroids[i * 256 + k * 4];
        __syncthreads();

        float e = 0.f;
        if (tid < VOC) {
            float dij = 0.f, djj = 0.f, dii = 0.f;
            const float4* cj = (const float4*)(centroids + (size_t)tid * 256);
            #pragma unroll 4
            for (int k = 0; k < 64; k++) {
                float4 b = cj[k];
                float4 a = *(const float4*)&s_buf[k * 4];
                dij += a.x * b.x + a.y * b.y + a.z * b.z + a.w * b.w;
                djj += b.x * b.x + b.y * b.y + b.z * b.z + b.w * b.w;
                dii += a.x * a.x + a.y * a.y + a.z * a.z + a.w * a.w;
            }
            float sim = dij * rsqrtf(dii * djj);
            e = __expf(sim);
        }
        float s = e;
        #pragma unroll
        for (int off = 32; off; off >>= 1) s += __shfl_xor(s, off);
        if (lane == 0) s_part[wave] = s;
        __syncthreads();
        float den = s_part[0] + s_part[1];
        if (tid < VOC) {
            float v = 0.15f * e / den;
            if (tid == i) v += 0.85f;
            soft[i * VOC + tid] = v;
        }
    }
}

// ============ kB: T/TlogT/lens per batch, soft staged in LDS ============
__global__ __launch_bounds__(256) void kB(
        const int* __restrict__ tgt_texts,   // [512, 25]
        const float* __restrict__ soft,      // [96, 96]
        float* __restrict__ T,               // [512, 96]
        float* __restrict__ TlogT,           // [512]
        int* __restrict__ lens)              // [512]
{
    const int b   = blockIdx.x;
    const int tid = threadIdx.x;
    __shared__ float s_soft[VOC * VOC];      // 36.9 KB
    __shared__ int   s_chars[NGT][LSEQ];

    for (int i = tid; i < VOC * VOC / 4; i += 256)
        ((float4*)s_soft)[i] = ((const float4*)soft)[i];
    for (int i = tid; i < NGT * LSEQ; i += 256)
        s_chars[i / LSEQ][i % LSEQ] = tgt_texts[b * NGT * LSEQ + i];
    __syncthreads();

    const int grp = tid >> 5, sub = tid & 31;
    for (int g = grp; g < NGT; g += 8) {
        int len = 0;
        float a0 = 0.f, a1 = 0.f, a2 = 0.f;
        for (int l = 0; l < LSEQ; l++) {
            int t = s_chars[g][l];
            if (t != VOC) {
                len++;
                const float* sr = s_soft + t * VOC;
                a0 += sr[sub]; a1 += sr[sub + 32]; a2 += sr[sub + 64];
            }
        }
        float inv = 1.f / (float)(len > 0 ? len : 1);
        a0 *= inv; a1 *= inv; a2 *= inv;
        float s = a0 + a1 + a2;
        #pragma unroll
        for (int off = 16; off; off >>= 1) s += __shfl_xor(s, off, 32);
        float denom = s + (float)VOC * KL_EPS;
        float t0 = (a0 + KL_EPS) / denom;
        float t1 = (a1 + KL_EPS) / denom;
        float t2 = (a2 + KL_EPS) / denom;
        const int bg = b * NGT + g;
        T[(size_t)bg * VOC + sub]      = t0;
        T[(size_t)bg * VOC + sub + 32] = t1;
        T[(size_t)bg * VOC + sub + 64] = t2;
        float tl = t0 * __logf(t0) + t1 * __logf(t1) + t2 * __logf(t2);
        #pragma unroll
        for (int off = 16; off; off >>= 1) tl += __shfl_xor(tl, off, 32);
        if (sub == 0) { TlogT[bg] = tl; lens[bg] = len; }
    }
}

// ============ kC: L1-cdist + class cost, 64x64 register-tiled ============
#define TR 64
#define TC 64
__global__ __launch_bounds__(256) void kC(
        const float* __restrict__ pred_ctrl,   // [NBQ, 50]
        const float* __restrict__ tgt_ctrl,    // [512, 50]
        const float* __restrict__ cost_class,  // [NBQ]
        float* __restrict__ out)               // [NBQ, 512]
{
    const int r0  = (blockIdx.x >> 3) * TR;   // 50 row tiles
    const int c0  = (blockIdx.x & 7) * TC;    // 8 col tiles
    const int tid = threadIdx.x;
    const int tx  = tid & 15;                 // col group (cols tx+16j)
    const int ty  = tid >> 4;                 // row group (rows ty*4+i)

    __shared__ float s_p[TR][52];
    __shared__ float s_t[TC][52];
    __shared__ float s_cc[TR];

    const float* pg = pred_ctrl + (size_t)r0 * 50;
    const float* tg = tgt_ctrl + (size_t)c0 * 50;
    for (int i = tid; i < TR * 50; i += 256) {
        int r = i / 50, d = i - r * 50;
        s_p[r][d] = pg[i];
        s_t[r][d] = tg[i];
    }
    if (tid < TR) s_cc[tid] = cost_class[r0 + tid];
    __syncthreads();

    float acc[4][4];
    #pragma unroll
    for (int i = 0; i < 4; i++)
        #pragma unroll
        for (int j = 0; j < 4; j++) acc[i][j] = 0.f;

    #pragma unroll
    for (int k = 0; k < 48; k += 4) {
        float4 p[4], t[4];
        #pragma unroll
        for (int i = 0; i < 4; i++) p[i] = *(const float4*)&s_p[ty * 4 + i][k];
        #pragma unroll
        for (int j = 0; j < 4; j++) t[j] = *(const float4*)&s_t[tx + 16 * j][k];
        #pragma unroll
        for (int i = 0; i < 4; i++)
            #pragma unroll
            for (int j = 0; j < 4; j++)
                acc[i][j] += fabsf(p[i].x - t[j].x) + fabsf(p[i].y - t[j].y)
                           + fabsf(p[i].z - t[j].z) + fabsf(p[i].w - t[j].w);
    }
    {   // k = 48, 49
        float2 p[4], t[4];
        #pragma unroll
        for (int i = 0; i < 4; i++) p[i] = *(const float2*)&s_p[ty * 4 + i][48];
        #pragma unroll
        for (int j = 0; j < 4; j++) t[j] = *(const float2*)&s_t[tx + 16 * j][48];
        #pragma unroll
        for (int i = 0; i < 4; i++)
            #pragma unroll
            for (int j = 0; j < 4; j++)
                acc[i][j] += fabsf(p[i].x - t[j].x) + fabsf(p[i].y - t[j].y);
    }

    #pragma unroll
    for (int i = 0; i < 4; i++) {
        const int row = ty * 4 + i;
        const float cc = s_cc[row];
        #pragma unroll
        for (int j = 0; j < 4; j++)
            out[(size_t)(r0 + row) * NCOL + c0 + tx + 16 * j] = acc[i][j] + cc;
    }
}

// ============ kT: add block-diagonal KL text cost (RMW on out) ============
__global__ __launch_bounds__(256) void kT(
        const float* __restrict__ logP,    // [NBQ, 96]
        const float* __restrict__ T,       // [512, 96]
        const float* __restrict__ TlogT,   // [512]
        const int* __restrict__ lens,      // [512]
        float* __restrict__ out)           // [NBQ, 512]
{
    const int r0  = blockIdx.x * 8;       // 400 blocks, 8 rows each
    const int b   = r0 / NQ;              // 8 | 200: no batch crossing
    const int tid = threadIdx.x;
    __shared__ float s_lp[8][VOC];
    __shared__ float s_Tt[VOC][NGT + 1];  // transposed, padded
    __shared__ float s_tl[NGT];
    __shared__ int   s_len[NGT];

    for (int i = tid; i < 8 * VOC; i += 256)
        s_lp[i / VOC][i % VOC] = logP[(size_t)r0 * VOC + i];
    for (int i = tid; i < NGT * VOC; i += 256) {
        int g = i / VOC, v = i - g * VOC;
        s_Tt[v][g] = T[(size_t)(b * NGT) * VOC + i];
    }
    if (tid < NGT) {
        s_tl[tid]  = TlogT[b * NGT + tid];
        s_len[tid] = lens[b * NGT + tid];
    }
    __syncthreads();

    const int g = tid & 31, rs = tid >> 5;
    float d = 0.f;
    #pragma unroll 8
    for (int v = 0; v < VOC; v++) d += s_lp[rs][v] * s_Tt[v][g];
    float val = (s_len[g] == 0) ? 100.f : (s_tl[g] - d);
    size_t o = (size_t)(r0 + rs) * NCOL + b * NGT + g;
    out[o] += val;
}

extern "C" void kernel_launch(void* const* d_in, const int* in_sizes, int n_in,
                              void* d_out, int out_size, void* d_ws, size_t ws_size,
                              hipStream_t stream) {
    const float* pred_logits = (const float*)d_in[0];
    const float* pred_ctrl   = (const float*)d_in[1];
    const float* pred_text   = (const float*)d_in[2];
    const float* tgt_ctrl    = (const float*)d_in[3];
    const int*   tgt_texts   = (const int*)d_in[4];
    const float* centroids   = (const float*)d_in[5];
    float* out = (float*)d_out;

    float* ws        = (float*)d_ws;
    float* logP      = ws;                          // 3200*96
    float* costclass = logP + (size_t)NBQ * VOC;    // 3200
    float* soft      = costclass + NBQ;             // 96*96 (16B aligned)
    float* T         = soft + VOC * VOC;            // 512*96
    float* TlogT     = T + (size_t)NCOL * VOC;      // 512
    int*   lens      = (int*)(TlogT + NCOL);        // 512

    kA<<<NBQ + VOC, 128, 0, stream>>>(pred_logits, pred_text, centroids,
                                      logP, costclass, soft);
    kB<<<BS, 256, 0, stream>>>(tgt_texts, soft, T, TlogT, lens);
    kC<<<400, 256, 0, stream>>>(pred_ctrl, tgt_ctrl, costclass, out);
    kT<<<400, 256, 0, stream>>>(logP, T, TlogT, lens, out);
}